// Round 7
// baseline (732.267 us; speedup 1.0000x reference)
//
#include <hip/hip_runtime.h>
#include <hip/hip_bf16.h>

// MultiHeadAttention: x(2,4096,768) @ W_qkv(768,2304) + b -> split q,k,v (H=8, dh=96)
// scores = q.k^T * 768^-0.5, softmax, out = attn @ v. Output fp32 (2,4096,768).
// R16: R15 showed kv-split at 256-thr was null: occupancy is LDS-capped (70KB -> 2
//     blocks/CU = 2 waves/SIMD) regardless of grid. Fix: 512-THREAD blocks (8 waves)
//     sharing ONE K/V staging set -- LDS/block unchanged (~68KB), waves/CU doubles
//     to 16 (4/SIMD). Grid 512 = 16 qtiles x 16 bh x 2 kv-halves = exactly 2
//     blocks/CU; combine (proven in R15) merges the kv-halves.
//     __launch_bounds__(512,4) pins VGPR<=128 (= exactly 4 waves/SIMD).
//     Per-thread staging halves (3 chunks vs 6) -> fewer VGPRs.
//     gemm_qkv/cvt/combine frozen (R13/R15). Fallback: unsplit 256-thr flash.

typedef __attribute__((ext_vector_type(8)))  short    bf16x8;   // MFMA A/B frag (4 VGPRs)
typedef __attribute__((ext_vector_type(4)))  float    floatx4;
typedef __attribute__((ext_vector_type(16))) float    floatx16; // 32x32 MFMA C/D
typedef __attribute__((ext_vector_type(8)))  unsigned short us8;
typedef __attribute__((ext_vector_type(4)))  unsigned short us4;

#define HEADS 8
#define DH 96
#define NSEQ 4096
#define DIM 768
// 768^-0.5 * log2(e): softmax runs in base-2 domain
#define SCALE2_F (0.03608439182435161f * 1.4426950408889634f)

// global -> LDS direct DMA, 16B per lane. LDS dest is wave-uniform base:
// lane l writes lds + l*16 bytes.
#define GLOAD16(g, s) __builtin_amdgcn_global_load_lds(                              \
    (const __attribute__((address_space(1))) unsigned int*)(g),                      \
    (__attribute__((address_space(3))) unsigned int*)(s), 16, 0, 0)

__device__ __forceinline__ unsigned short f2bf(float f) {
    union { float f; unsigned u; } v; v.f = f;
    unsigned r = v.u + 0x7fffu + ((v.u >> 16) & 1u);  // RN-even
    return (unsigned short)(r >> 16);
}

__device__ __forceinline__ unsigned pk2(float a, float b) {
    float2 t; t.x = a; t.y = b;
    __hip_bfloat162 r = __float22bfloat162_rn(t);
    return *(unsigned*)&r;
}

// Build PV A-frag (m=q=lane&31, k-step of 16 kv) from S^T C-regs c[0..7].
__device__ __forceinline__ bf16x8 mk_pfrag(float c0, float c1, float c2, float c3,
                                           float c4, float c5, float c6, float c7, int hB) {
    unsigned pl0 = pk2(c0, c1), pl1 = pk2(c2, c3);
    unsigned pu0 = pk2(c4, c5), pu1 = pk2(c6, c7);
    unsigned s0 = hB ? pl0 : pu0, s1 = hB ? pl1 : pu1;
    unsigned r0 = (unsigned)__shfl_xor((int)s0, 32);
    unsigned r1 = (unsigned)__shfl_xor((int)s1, 32);
    union { unsigned u[4]; bf16x8 v; } f;
    f.u[0] = hB ? r0 : pl0;
    f.u[1] = hB ? r1 : pl1;
    f.u[2] = hB ? pu0 : r0;
    f.u[3] = hB ? pu1 : r1;
    return f.v;
}

// ---------------- cvt: x (fp32)->xb (bf16) AND W (fp32)->Wt (bf16 transposed) -------
__global__ __launch_bounds__(256) void cvt(const float* __restrict__ x,
                                           const float* __restrict__ w,
                                           unsigned short* __restrict__ xb,
                                           unsigned short* __restrict__ wt) {
    __shared__ unsigned short sm[64][33];
    const int bid = blockIdx.x;
    const int t = threadIdx.x;
    if (bid < 6144) {
        int i = bid * 256 + t;
        float4 v = ((const float4*)x)[i];
        us4 o; o.x = f2bf(v.x); o.y = f2bf(v.y); o.z = f2bf(v.z); o.w = f2bf(v.w);
        ((us4*)xb)[i] = o;
    } else {
        int wb = bid - 6144;
        int c0 = (wb % 72) * 32, k0 = (wb / 72) * 64;
        int cl = t & 31, kl0 = t >> 5;
        for (int i = 0; i < 8; ++i) {
            int kl = kl0 + i * 8;
            sm[kl][cl] = f2bf(w[(k0 + kl) * 2304 + c0 + cl]);
        }
        __syncthreads();
        int kl2 = t & 63, cl0 = t >> 6;
        for (int i = 0; i < 8; ++i) {
            int cl2 = cl0 + i * 4;
            wt[(c0 + cl2) * 768 + k0 + kl2] = sm[kl2][cl2];
        }
    }
}

// ---------------- gemm_qkv: fused qk + v GEMMs, 1152 blocks, XCD-chunked ------------
// (identical to R13)
__global__ __launch_bounds__(256) void gemm_qkv(const unsigned short* __restrict__ xb,
                                                const unsigned short* __restrict__ wt,
                                                const float* __restrict__ bias,
                                                unsigned short* __restrict__ qb,
                                                unsigned short* __restrict__ kb,
                                                unsigned short* __restrict__ vt) {
    __shared__ unsigned short As[2][128 * 64];
    __shared__ unsigned short Bs[2][128 * 64];
    const int tid = threadIdx.x;
    const int lane = tid & 63, wv = tid >> 6;
    const int n15 = lane & 15, quad = lane >> 4;
    const int x7q = n15 & 7;                       // reader row&7
    const int mw = (wv >> 1) * 64, nw = (wv & 1) * 64;
    const int lrow = lane >> 3;                    // writer row&7
    const int lcolsw = ((lane & 7) ^ lrow) * 8;    // inverse-swizzled source col (elems)
    const int lofs = wv * 8 * 64;
    floatx4 acc[4][4] = {};

    const int raw = blockIdx.x;
    const int id = (raw & 7) * 144 + (raw >> 3);   // chunked XCD swizzle (bijective)
    const bool isv = id >= 768;
    int m0, c0;
    const unsigned short *gA, *gB;
    if (!isv) {                                    // qk: m-major
        m0 = (id / 12) * 128; c0 = (id % 12) * 128;
        gA = xb + (size_t)(m0 + wv * 8 + lrow) * 768 + lcolsw;
        gB = wt + (size_t)(c0 + wv * 8 + lrow) * 768 + lcolsw;
    } else {                                       // v: c-major (m0=dv, c0=n)
        int iv = id - 768;
        c0 = (iv / 6) * 128; m0 = (iv % 6) * 128;
        gA = wt + (size_t)(1536 + m0 + wv * 8 + lrow) * 768 + lcolsw;
        gB = xb + (size_t)(c0 + wv * 8 + lrow) * 768 + lcolsw;
    }

    auto stage = [&](int b, int kt) {
#pragma unroll
        for (int i = 0; i < 4; ++i) {
            GLOAD16(gA + (size_t)i * 32 * 768 + kt * 64, &As[b][lofs + i * 32 * 64]);
            GLOAD16(gB + (size_t)i * 32 * 768 + kt * 64, &Bs[b][lofs + i * 32 * 64]);
        }
    };

    stage(0, 0);
    __syncthreads();                       // vmcnt(0) drain: tile 0 ready
#pragma unroll 2
    for (int kt = 0; kt < 12; ++kt) {
        const int cur = kt & 1;
        if (kt < 11) stage(cur ^ 1, kt + 1);   // in flight across the MFMA phase
#pragma unroll
        for (int ks = 0; ks < 2; ++ks) {
            bf16x8 af[4], bfr[4];
            for (int mt = 0; mt < 4; ++mt)
                af[mt] = *(const bf16x8*)&As[cur][(mw + mt * 16 + n15) * 64
                                                 + (((ks << 2) + quad) ^ x7q) * 8];
            for (int nt = 0; nt < 4; ++nt)
                bfr[nt] = *(const bf16x8*)&Bs[cur][(nw + nt * 16 + n15) * 64
                                                  + (((ks << 2) + quad) ^ x7q) * 8];
            for (int mt = 0; mt < 4; ++mt)
                for (int nt = 0; nt < 4; ++nt)
                    acc[mt][nt] = __builtin_amdgcn_mfma_f32_16x16x32_bf16(af[mt], bfr[nt], acc[mt][nt], 0, 0, 0);
        }
        __syncthreads();                   // one barrier/iter: tile kt+1 ready, tile kt dead
    }

    if (!isv) {
        for (int nt = 0; nt < 4; ++nt) {
            int c = c0 + nw + nt * 16 + n15;      // < 1536
            float bv = bias[c];
            int which = c / 768, rem = c % 768;
            int h = rem / 96, d = rem % 96;
            for (int mt = 0; mt < 4; ++mt) {
                for (int r = 0; r < 4; ++r) {
                    int m = m0 + mw + mt * 16 + quad * 4 + r;
                    int b = m >> 12, n = m & 4095;
                    float val = acc[mt][nt][r] + bv;
                    int bh = b * HEADS + h;
                    if (which == 0) qb[(bh * NSEQ + n) * DH + d] = f2bf(val * SCALE2_F);
                    else            kb[(bh * NSEQ + n) * DH + d] = f2bf(val);
                }
            }
        }
    } else {
        for (int mt = 0; mt < 4; ++mt) {
            for (int r = 0; r < 4; ++r) {
                int dv = m0 + mw + mt * 16 + quad * 4 + r;     // < 768
                float bv = bias[1536 + dv];
                int h = dv / 96, d = dv % 96;
                for (int nt = 0; nt < 4; ++nt) {
                    int ng = c0 + nw + nt * 16 + n15;
                    int b = ng >> 12, n = ng & 4095;
                    vt[((size_t)(b * HEADS + h) * DH + d) * NSEQ + n] = f2bf(acc[mt][nt][r] + bv);
                }
            }
        }
    }
}

// ---------------- flash8: 512-thr (8 waves), kv-split x2, shared K/V staging --------
// Grid 512 = bh(16) x half(2, bit4) x qtile(16, bits 5-8). Each block: 256 q-rows
// (wave wv owns q0+wv*32), 32 kv-tiles of 64. K dbuf 2x8192el swz, V tribuf
// 3x6144el swz -- SAME proven layouts; 8 waves share them -> 4 waves/SIMD.
// Staging: 1536 16B-chunks/tile over 512 thr = 3/thread (wave-uniform K/V role).
// Writes UN-normalized partial O + partial lsum (combine merges halves).
__global__ __launch_bounds__(512, 4) void flash8(const unsigned short* __restrict__ qb,
                                                 const unsigned short* __restrict__ kb,
                                                 const unsigned short* __restrict__ vt,
                                                 float* __restrict__ outp,
                                                 float* __restrict__ lp) {
    __shared__ unsigned short sm[34816];   // K: [0,16384) ; V: [16384, 34816) (3 slots)

    const int tid = threadIdx.x;
    const int lane = tid & 63, wv = tid >> 6;        // wv in [0,8)
    const int l31 = lane & 31, h = lane >> 5;
    const int x7 = l31 & 7;
    const int id = blockIdx.x;                       // 512 blocks
    const int bh = id & 15;
    const int half = (id >> 4) & 1;
    const int q0 = (id >> 5) * 256 + wv * 32;
    const int NT = 32;

    const unsigned short* kgb = kb + (size_t)bh * NSEQ * DH + (size_t)half * 2048 * DH;
    const unsigned short* vgb = vt + (size_t)bh * DH * NSEQ + (size_t)half * 2048;

    // ---- Q B-frags in registers ----
    bf16x8 qf[6];
    {
        const unsigned short* qrow = qb + (size_t)(bh * NSEQ + q0 + l31) * DH;
#pragma unroll
        for (int ks = 0; ks < 6; ++ks)
            qf[ks] = *(const bf16x8*)&qrow[ks * 16 + h * 8];
    }

    // ---- loop-invariant LDS read offsets (swizzled; same as proven 256-thr) ----
    int kofs[2][6];
#pragma unroll
    for (int kt = 0; kt < 2; ++kt)
#pragma unroll
        for (int ks = 0; ks < 6; ++ks) {
            int b = 2 * ks + h;
            int bs = (b < 8) ? (b ^ x7) : (8 + ((b - 8) ^ x7));
            kofs[kt][ks] = (kt * 32 + l31) * 128 + bs * 8;
        }
    int vofs[3][4];
#pragma unroll
    for (int dt = 0; dt < 3; ++dt)
#pragma unroll
        for (int s = 0; s < 4; ++s)
            vofs[dt][s] = (dt * 32 + l31) * 64 + ((2 * s + h) ^ x7) * 8;

    // ---- staging map: 3 chunks/thread over 1536 = K(768) + V(768) ----
    const unsigned short* gptr[3];   // advanced per tile by step[i]
    int step[3], wofs[3], wbase[3];  // wbase: 0 => K region (slot-selected), 1 => V
#pragma unroll
    for (int i = 0; i < 3; ++i) {
        int tb = i * 512 + tid;
        if (tb < 768) {              // K chunk: r<64 rows of 12 slots
            int r = tb / 12, bb = tb % 12;
            gptr[i] = kgb + r * 96 + bb * 8;
            step[i] = 6144;
            int bs = (bb < 8) ? (bb ^ (r & 7)) : (8 + ((bb - 8) ^ (r & 7)));
            wofs[i] = r * 128 + bs * 8;
            wbase[i] = 0;
        } else {                     // V chunk: d<96 rows of 8 slots
            int c = tb - 768;
            int d = c / 8, b2 = c & 7;
            gptr[i] = vgb + d * 4096 + b2 * 8;
            step[i] = 64;
            wofs[i] = d * 64 + ((b2 ^ (d & 7))) * 8;
            wbase[i] = 1;
        }
    }

    const floatx16 z16 = (floatx16)(0.f);

    // ---- prologue: tile0 -> K0/V0; tile1 -> regs; S^T[0] ----
    us8 st[3];
#pragma unroll
    for (int i = 0; i < 3; ++i) { st[i] = *(const us8*)gptr[i]; gptr[i] += step[i]; }
#pragma unroll
    for (int i = 0; i < 3; ++i) {
        unsigned short* dst = sm + (wbase[i] ? 16384 : 0) + wofs[i];
        *(us8*)dst = st[i];
    }
#pragma unroll
    for (int i = 0; i < 3; ++i) { st[i] = *(const us8*)gptr[i]; gptr[i] += step[i]; }
    __syncthreads();

    floatx16 stA[2], stB[2];
#pragma unroll
    for (int ks = 0; ks < 6; ++ks)
#pragma unroll
        for (int kt = 0; kt < 2; ++kt) {
            bf16x8 ak = *(const bf16x8*)&sm[kofs[kt][ks]];
            stA[kt] = __builtin_amdgcn_mfma_f32_32x32x16_bf16(ak, qf[ks], ks == 0 ? z16 : stA[kt], 0, 0, 0);
        }

    floatx16 o[3] = {};        // O[d-tile]: col=d=l31, rows=q
    float lsum = 0.f;

    // body(kv): cur = S^T[kv] (ready); nxt <- S^T[kv+1]. ONE barrier.
    auto body = [&](int kv, floatx16 (&cur)[2], floatx16 (&nxt)[2]) {
        if (kv < NT - 1) {
            const int kslot = ((kv + 1) & 1) * 8192;
            const int vslot = 16384 + ((kv + 1) % 3) * 6144;
#pragma unroll
            for (int i = 0; i < 3; ++i) {
                unsigned short* dst = sm + (wbase[i] ? vslot : kslot) + wofs[i];
                *(us8*)dst = st[i];
            }
            if (kv < NT - 2) {
#pragma unroll
                for (int i = 0; i < 3; ++i) { st[i] = *(const us8*)gptr[i]; gptr[i] += step[i]; }
            }
        }
        __syncthreads();                       // tile kv+1 K/V visible

        // ---- S^T[kv+1] (matrix pipe), zero-C init ----
        if (kv < NT - 1) {
            const unsigned short* Kn = sm + ((kv + 1) & 1) * 8192;
#pragma unroll
            for (int ks = 0; ks < 6; ++ks)
#pragma unroll
                for (int kt = 0; kt < 2; ++kt) {
                    bf16x8 ak = *(const bf16x8*)&Kn[kofs[kt][ks]];
                    nxt[kt] = __builtin_amdgcn_mfma_f32_32x32x16_bf16(ak, qf[ks], ks == 0 ? z16 : nxt[kt], 0, 0, 0);
                }
        }

        // ---- exp2/lsum/pack of tile kv (VALU pipe, overlaps S^T MFMAs) ----
#pragma unroll
        for (int kt = 0; kt < 2; ++kt)
#pragma unroll
            for (int rg = 0; rg < 16; ++rg) {
                float p = __builtin_amdgcn_exp2f(cur[kt][rg]);
                cur[kt][rg] = p;
                lsum += p;
            }
        bf16x8 pf[4];
        pf[0] = mk_pfrag(cur[0][0], cur[0][1], cur[0][2], cur[0][3],
                         cur[0][4], cur[0][5], cur[0][6], cur[0][7], h);
        pf[1] = mk_pfrag(cur[0][8], cur[0][9], cur[0][10], cur[0][11],
                         cur[0][12], cur[0][13], cur[0][14], cur[0][15], h);
        pf[2] = mk_pfrag(cur[1][0], cur[1][1], cur[1][2], cur[1][3],
                         cur[1][4], cur[1][5], cur[1][6], cur[1][7], h);
        pf[3] = mk_pfrag(cur[1][8], cur[1][9], cur[1][10], cur[1][11],
                         cur[1][12], cur[1][13], cur[1][14], cur[1][15], h);

        // ---- O += P V (tile kv) from V slot kv%3 ----
        const unsigned short* Vc = sm + 16384 + (kv % 3) * 6144;
#pragma unroll
        for (int s = 0; s < 4; ++s)
#pragma unroll
            for (int dt = 0; dt < 3; ++dt) {
                bf16x8 bv = *(const bf16x8*)&Vc[vofs[dt][s]];
                o[dt] = __builtin_amdgcn_mfma_f32_32x32x16_bf16(pf[s], bv, o[dt], 0, 0, 0);
            }
    };

    for (int kv = 0; kv < NT; kv += 2) {
        body(kv, stA, stB);
        body(kv + 1, stB, stA);
    }

    // ---- partial lsum + un-normalized partial O ----
    lsum += __shfl_xor(lsum, 32);
    const int b = bh >> 3, hd = bh & 7;
    if (h == 0) lp[(size_t)(half * 16 + bh) * NSEQ + q0 + l31] = lsum;
    float* ob = outp + (size_t)half * (2 * NSEQ * DIM);
#pragma unroll
    for (int rg = 0; rg < 16; ++rg) {
        int row = (rg & 3) + 8 * (rg >> 2) + 4 * h;
        int q = q0 + row;
        float* op = ob + (size_t)(b * NSEQ + q) * DIM + hd * DH;
#pragma unroll
        for (int dt = 0; dt < 3; ++dt)
            op[dt * 32 + l31] = o[dt][rg];
    }
}

// ---------------- flash (fallback, unsplit, 256-thr; R11-identical) -----------------
__global__ __launch_bounds__(256, 2) void flash(const unsigned short* __restrict__ qb,
                                                const unsigned short* __restrict__ kb,
                                                const unsigned short* __restrict__ vt,
                                                float* __restrict__ outp) {
    __shared__ unsigned short sm[34816];
    __shared__ float l_all[128];

    const int tid = threadIdx.x;
    const int lane = tid & 63, wv = tid >> 6;
    const int l31 = lane & 31, h = lane >> 5;
    const int x7 = l31 & 7;
    const int id = blockIdx.x;
    const int bh = id & 15;
    const int q0 = (id >> 4) * 128 + wv * 32;

    const unsigned short* kgb = kb + (size_t)bh * NSEQ * DH;
    const unsigned short* vgb = vt + (size_t)bh * DH * NSEQ;

    bf16x8 qf[6];
    {
        const unsigned short* qrow = qb + (size_t)(bh * NSEQ + q0 + l31) * DH;
#pragma unroll
        for (int ks = 0; ks < 6; ++ks)
            qf[ks] = *(const bf16x8*)&qrow[ks * 16 + h * 8];
    }

    int kofs[2][6];
#pragma unroll
    for (int kt = 0; kt < 2; ++kt)
#pragma unroll
        for (int ks = 0; ks < 6; ++ks) {
            int b = 2 * ks + h;
            int bs = (b < 8) ? (b ^ x7) : (8 + ((b - 8) ^ x7));
            kofs[kt][ks] = (kt * 32 + l31) * 128 + bs * 8;
        }
    int vofs[3][4];
#pragma unroll
    for (int dt = 0; dt < 3; ++dt)
#pragma unroll
        for (int s = 0; s < 4; ++s)
            vofs[dt][s] = (dt * 32 + l31) * 64 + ((2 * s + h) ^ x7) * 8;

    int goffk[3], goffv[3], wofk[3], wofv[3];
#pragma unroll
    for (int i = 0; i < 3; ++i) {
        int tb = i * 256 + tid;
        int r = tb / 12, bb = tb % 12;
        goffk[i] = r * 96 + bb * 8;
        int bs = (bb < 8) ? (bb ^ (r & 7)) : (8 + ((bb - 8) ^ (r & 7)));
        wofk[i] = r * 128 + bs * 8;
        int d = tb >> 3, b2 = tb & 7;
        goffv[i] = d * 4096 + b2 * 8;
        wofv[i] = d * 64 + ((b2 ^ (d & 7))) * 8;
    }

    const floatx16 z16 = (floatx16)(0.f);

    us8 kr[3], vr[3];
    const unsigned short* kpf = kgb;
    const unsigned short* vpf = vgb;
#pragma unroll
    for (int i = 0; i < 3; ++i) { kr[i] = *(const us8*)&kpf[goffk[i]]; vr[i] = *(const us8*)&vpf[goffv[i]]; }
    kpf += 6144; vpf += 64;
#pragma unroll
    for (int i = 0; i < 3; ++i) { *(us8*)&sm[wofk[i]] = kr[i]; *(us8*)&sm[16384 + wofv[i]] = vr[i]; }
#pragma unroll
    for (int i = 0; i < 3; ++i) { kr[i] = *(const us8*)&kpf[goffk[i]]; vr[i] = *(const us8*)&vpf[goffv[i]]; }
    kpf += 6144; vpf += 64;
    __syncthreads();

    floatx16 stA[2], stB[2];
#pragma unroll
    for (int ks = 0; ks < 6; ++ks)
#pragma unroll
        for (int kt = 0; kt < 2; ++kt) {
            bf16x8 ak = *(const bf16x8*)&sm[kofs[kt][ks]];
            stA[kt] = __builtin_amdgcn_mfma_f32_32x32x16_bf16(ak, qf[ks], ks == 0 ? z16 : stA[kt], 0, 0, 0);
        }

    floatx16 o[3] = {};
    float lsum = 0.f;

    auto body = [&](int kv, floatx16 (&cur)[2], floatx16 (&nxt)[2]) {
        if (kv < 63) {
            unsigned short* Kd = sm + ((kv + 1) & 1) * 8192;
            unsigned short* Vd = sm + 16384 + ((kv + 1) % 3) * 6144;
#pragma unroll
            for (int i = 0; i < 3; ++i) { *(us8*)&Kd[wofk[i]] = kr[i]; *(us8*)&Vd[wofv[i]] = vr[i]; }
            if (kv < 62) {
#pragma unroll
                for (int i = 0; i < 3; ++i) { kr[i] = *(const us8*)&kpf[goffk[i]]; vr[i] = *(const us8*)&vpf[goffv[i]]; }
                kpf += 6144; vpf += 64;
            }
        }
        __syncthreads();

        if (kv < 63) {
            const unsigned short* Kn = sm + ((kv + 1) & 1) * 8192;
#pragma unroll
            for (int ks = 0; ks < 6; ++ks)
#pragma unroll
                for (int kt = 0; kt < 2; ++kt) {
                    bf16x8 ak = *(const bf16x8*)&Kn[kofs[kt][ks]];
                    nxt[kt] = __builtin_amdgcn_mfma_f32_32x32x16_bf16(ak, qf[ks], ks == 0 ? z16 : nxt[kt], 0, 0, 0);
                }
        }

#pragma unroll
        for (int kt = 0; kt < 2; ++kt)
#pragma unroll
            for (int rg = 0; rg < 16; ++rg) {
                float p = __builtin_amdgcn_exp2f(cur[kt][rg]);
                cur[kt][rg] = p;
                lsum += p;
            }
        bf16x8 pf[4];
        pf[0] = mk_pfrag(cur[0][0], cur[0][1], cur[0][2], cur[0][3],
                         cur[0][4], cur[0][5], cur[0][6], cur[0][7], h);
        pf[1] = mk_pfrag(cur[0][8], cur[0][9], cur[0][10], cur[0][11],
                         cur[0][12], cur[0][13], cur[0][14], cur[0][15], h);
        pf[2] = mk_pfrag(cur[1][0], cur[1][1], cur[1][2], cur[1][3],
                         cur[1][4], cur[1][5], cur[1][6], cur[1][7], h);
        pf[3] = mk_pfrag(cur[1][8], cur[1][9], cur[1][10], cur[1][11],
                         cur[1][12], cur[1][13], cur[1][14], cur[1][15], h);

        const unsigned short* Vc = sm + 16384 + (kv % 3) * 6144;
#pragma unroll
        for (int s = 0; s < 4; ++s)
#pragma unroll
            for (int dt = 0; dt < 3; ++dt) {
                bf16x8 bv = *(const bf16x8*)&Vc[vofs[dt][s]];
                o[dt] = __builtin_amdgcn_mfma_f32_32x32x16_bf16(pf[s], bv, o[dt], 0, 0, 0);
            }
    };

    for (int kv = 0; kv < 64; kv += 2) {
        body(kv, stA, stB);
        body(kv + 1, stB, stA);
    }

    lsum += __shfl_xor(lsum, 32);
    if (h == 0) l_all[wv * 32 + l31] = lsum;
    __syncthreads();

    const int b = bh >> 3, hd = bh & 7;
#pragma unroll
    for (int rg = 0; rg < 16; ++rg) {
        int row = (rg & 3) + 8 * (rg >> 2) + 4 * h;
        float inv = 1.0f / l_all[wv * 32 + row];
        int q = q0 + row;
        float* op = outp + (size_t)(b * NSEQ + q) * DIM + hd * DH;
#pragma unroll
        for (int dt = 0; dt < 3; ++dt)
            op[dt * 32 + l31] = o[dt][rg] * inv;
    }
}

// ---------------- combine: out = (O0 + O1) / (l0 + l1) -----------------------------
__global__ __launch_bounds__(256) void combine(const float* __restrict__ P,
                                               const float* __restrict__ ls,
                                               float* __restrict__ out) {
    int i = blockIdx.x * 256 + threadIdx.x;      // float4 index, total 1572864
    int row = i / 192;                            // b*4096 + q  (0..8191)
    int hd = (i % 192) / 24;
    int b = row >> 12, q = row & 4095;
    int bh = b * HEADS + hd;
    float l = ls[bh * NSEQ + q] + ls[16 * NSEQ + bh * NSEQ + q];
    float inv = 1.0f / l;
    float4 v0 = ((const float4*)P)[i];
    float4 v1 = ((const float4*)P)[1572864 + i];
    float4 r;
    r.x = (v0.x + v1.x) * inv;
    r.y = (v0.y + v1.y) * inv;
    r.z = (v0.z + v1.z) * inv;
    r.w = (v0.w + v1.w) * inv;
    ((float4*)out)[i] = r;
}

extern "C" void kernel_launch(void* const* d_in, const int* in_sizes, int n_in,
                              void* d_out, int out_size, void* d_ws, size_t ws_size,
                              hipStream_t stream) {
    const float* x    = (const float*)d_in[0];   // 2*4096*768
    const float* W    = (const float*)d_in[1];   // 768*2304
    const float* bias = (const float*)d_in[2];   // 2304
    float* out = (float*)d_out;

    char* ws = (char*)d_ws;
    unsigned short* xb = (unsigned short*)(ws);                    // 8192*768 bf16
    unsigned short* wt = (unsigned short*)(ws + 12582912);         // 2304*768 bf16 (transposed)
    unsigned short* qb = (unsigned short*)(ws + 16121856);         // [16][4096][96]
    unsigned short* kb = (unsigned short*)(ws + 28704768);         // [16][4096][96]
    unsigned short* vt = (unsigned short*)(ws + 41287680);         // [16][96][4096]
    float* Opart = (float*)(ws + 53870592);                        // [2][2][4096][768] fp32
    float* lpart = (float*)(ws + 104202240);                       // [2][16][4096] fp32
    const size_t WS_NEED = 104726528;

    cvt<<<7008, 256, 0, stream>>>(x, W, xb, wt);
    gemm_qkv<<<1152, 256, 0, stream>>>(xb, wt, bias, qb, kb, vt);
    if (ws_size >= WS_NEED) {
        flash8<<<512, 512, 0, stream>>>(qb, kb, vt, Opart, lpart);
        combine<<<6144, 256, 0, stream>>>(Opart, lpart, out);
    } else {
        flash<<<512, 256, 0, stream>>>(qb, kb, vt, out);
    }
}

// Round 9
// 245.134 us; speedup vs baseline: 2.9872x; 2.9872x over previous
//
#include <hip/hip_runtime.h>
#include <hip/hip_bf16.h>

// MultiHeadAttention: x(2,4096,768) @ W_qkv(768,2304) + b -> split q,k,v (H=8, dh=96)
// scores = q.k^T * 768^-0.5, softmax, out = attn @ v. Output fp32 (2,4096,768).
// R18: REVERT R17's inline-asm v_cvt_pk_bf16_f32 -- measured NOT RNE-equivalent on
//     gfx950 (absmax 0.0184 vs 0.00049: ~1 bf16 ulp, truncation-style). pk2 back to
//     __float22bfloat162_rn (bit-exact with R13's passing runs); cvt x-path back to
//     f2bf. KEEP the merged cvt kernel (3 launches total; passed in R15/R16).
//     gemm_qkv + flash byte-identical to R13 (250.4us best).

typedef __attribute__((ext_vector_type(8)))  short    bf16x8;   // MFMA A/B frag (4 VGPRs)
typedef __attribute__((ext_vector_type(4)))  float    floatx4;
typedef __attribute__((ext_vector_type(16))) float    floatx16; // 32x32 MFMA C/D
typedef __attribute__((ext_vector_type(8)))  unsigned short us8;
typedef __attribute__((ext_vector_type(4)))  unsigned short us4;

#define HEADS 8
#define DH 96
#define NSEQ 4096
#define DIM 768
// 768^-0.5 * log2(e): softmax runs in base-2 domain
#define SCALE2_F (0.03608439182435161f * 1.4426950408889634f)

// global -> LDS direct DMA, 16B per lane. LDS dest is wave-uniform base:
// lane l writes lds + l*16 bytes.
#define GLOAD16(g, s) __builtin_amdgcn_global_load_lds(                              \
    (const __attribute__((address_space(1))) unsigned int*)(g),                      \
    (__attribute__((address_space(3))) unsigned int*)(s), 16, 0, 0)

__device__ __forceinline__ unsigned short f2bf(float f) {
    union { float f; unsigned u; } v; v.f = f;
    unsigned r = v.u + 0x7fffu + ((v.u >> 16) & 1u);  // RN-even
    return (unsigned short)(r >> 16);
}

// RNE packed fp32->bf16 (compiler lowering; R17's v_cvt_pk_bf16_f32 asm is NOT RNE
// on gfx950 -- failed absmax by ~1 bf16 ulp. Keep the intrinsic.)
__device__ __forceinline__ unsigned pk2(float a, float b) {
    float2 t; t.x = a; t.y = b;
    __hip_bfloat162 r = __float22bfloat162_rn(t);
    return *(unsigned*)&r;
}

// Build PV A-frag (m=q=lane&31, k-step of 16 kv) from S^T C-regs c[0..7].
__device__ __forceinline__ bf16x8 mk_pfrag(float c0, float c1, float c2, float c3,
                                           float c4, float c5, float c6, float c7, int hB) {
    unsigned pl0 = pk2(c0, c1), pl1 = pk2(c2, c3);
    unsigned pu0 = pk2(c4, c5), pu1 = pk2(c6, c7);
    unsigned s0 = hB ? pl0 : pu0, s1 = hB ? pl1 : pu1;
    unsigned r0 = (unsigned)__shfl_xor((int)s0, 32);
    unsigned r1 = (unsigned)__shfl_xor((int)s1, 32);
    union { unsigned u[4]; bf16x8 v; } f;
    f.u[0] = hB ? r0 : pl0;
    f.u[1] = hB ? r1 : pl1;
    f.u[2] = hB ? pu0 : r0;
    f.u[3] = hB ? pu1 : r1;
    return f.v;
}

// ---------------- cvt: x (fp32)->xb (bf16) AND W (fp32)->Wt (bf16 transposed) -------
// blocks [0,6144): x conversion; blocks [6144, 6144+864): W transpose-convert.
__global__ __launch_bounds__(256) void cvt(const float* __restrict__ x,
                                           const float* __restrict__ w,
                                           unsigned short* __restrict__ xb,
                                           unsigned short* __restrict__ wt) {
    __shared__ unsigned short sm[64][33];
    const int bid = blockIdx.x;
    const int t = threadIdx.x;
    if (bid < 6144) {
        int i = bid * 256 + t;
        float4 v = ((const float4*)x)[i];
        us4 o; o.x = f2bf(v.x); o.y = f2bf(v.y); o.z = f2bf(v.z); o.w = f2bf(v.w);
        ((us4*)xb)[i] = o;
    } else {
        int wb = bid - 6144;
        int c0 = (wb % 72) * 32, k0 = (wb / 72) * 64;
        int cl = t & 31, kl0 = t >> 5;
        for (int i = 0; i < 8; ++i) {
            int kl = kl0 + i * 8;
            sm[kl][cl] = f2bf(w[(k0 + kl) * 2304 + c0 + cl]);
        }
        __syncthreads();
        int kl2 = t & 63, cl0 = t >> 6;
        for (int i = 0; i < 8; ++i) {
            int cl2 = cl0 + i * 4;
            wt[(c0 + cl2) * 768 + k0 + kl2] = sm[kl2][cl2];
        }
    }
}

// ---------------- gemm_qkv: fused qk + v GEMMs, 1152 blocks, XCD-chunked ------------
// (identical to R13)
__global__ __launch_bounds__(256) void gemm_qkv(const unsigned short* __restrict__ xb,
                                                const unsigned short* __restrict__ wt,
                                                const float* __restrict__ bias,
                                                unsigned short* __restrict__ qb,
                                                unsigned short* __restrict__ kb,
                                                unsigned short* __restrict__ vt) {
    __shared__ unsigned short As[2][128 * 64];
    __shared__ unsigned short Bs[2][128 * 64];
    const int tid = threadIdx.x;
    const int lane = tid & 63, wv = tid >> 6;
    const int n15 = lane & 15, quad = lane >> 4;
    const int x7q = n15 & 7;                       // reader row&7
    const int mw = (wv >> 1) * 64, nw = (wv & 1) * 64;
    const int lrow = lane >> 3;                    // writer row&7
    const int lcolsw = ((lane & 7) ^ lrow) * 8;    // inverse-swizzled source col (elems)
    const int lofs = wv * 8 * 64;
    floatx4 acc[4][4] = {};

    const int raw = blockIdx.x;
    const int id = (raw & 7) * 144 + (raw >> 3);   // chunked XCD swizzle (bijective)
    const bool isv = id >= 768;
    int m0, c0;
    const unsigned short *gA, *gB;
    if (!isv) {                                    // qk: m-major
        m0 = (id / 12) * 128; c0 = (id % 12) * 128;
        gA = xb + (size_t)(m0 + wv * 8 + lrow) * 768 + lcolsw;
        gB = wt + (size_t)(c0 + wv * 8 + lrow) * 768 + lcolsw;
    } else {                                       // v: c-major (m0=dv, c0=n)
        int iv = id - 768;
        c0 = (iv / 6) * 128; m0 = (iv % 6) * 128;
        gA = wt + (size_t)(1536 + m0 + wv * 8 + lrow) * 768 + lcolsw;
        gB = xb + (size_t)(c0 + wv * 8 + lrow) * 768 + lcolsw;
    }

    auto stage = [&](int b, int kt) {
#pragma unroll
        for (int i = 0; i < 4; ++i) {
            GLOAD16(gA + (size_t)i * 32 * 768 + kt * 64, &As[b][lofs + i * 32 * 64]);
            GLOAD16(gB + (size_t)i * 32 * 768 + kt * 64, &Bs[b][lofs + i * 32 * 64]);
        }
    };

    stage(0, 0);
    __syncthreads();                       // vmcnt(0) drain: tile 0 ready
#pragma unroll 2
    for (int kt = 0; kt < 12; ++kt) {
        const int cur = kt & 1;
        if (kt < 11) stage(cur ^ 1, kt + 1);   // in flight across the MFMA phase
#pragma unroll
        for (int ks = 0; ks < 2; ++ks) {
            bf16x8 af[4], bfr[4];
            for (int mt = 0; mt < 4; ++mt)
                af[mt] = *(const bf16x8*)&As[cur][(mw + mt * 16 + n15) * 64
                                                 + (((ks << 2) + quad) ^ x7q) * 8];
            for (int nt = 0; nt < 4; ++nt)
                bfr[nt] = *(const bf16x8*)&Bs[cur][(nw + nt * 16 + n15) * 64
                                                  + (((ks << 2) + quad) ^ x7q) * 8];
            for (int mt = 0; mt < 4; ++mt)
                for (int nt = 0; nt < 4; ++nt)
                    acc[mt][nt] = __builtin_amdgcn_mfma_f32_16x16x32_bf16(af[mt], bfr[nt], acc[mt][nt], 0, 0, 0);
        }
        __syncthreads();                   // one barrier/iter: tile kt+1 ready, tile kt dead
    }

    if (!isv) {
        for (int nt = 0; nt < 4; ++nt) {
            int c = c0 + nw + nt * 16 + n15;      // < 1536
            float bv = bias[c];
            int which = c / 768, rem = c % 768;
            int h = rem / 96, d = rem % 96;
            for (int mt = 0; mt < 4; ++mt) {
                for (int r = 0; r < 4; ++r) {
                    int m = m0 + mw + mt * 16 + quad * 4 + r;
                    int b = m >> 12, n = m & 4095;
                    float val = acc[mt][nt][r] + bv;
                    int bh = b * HEADS + h;
                    if (which == 0) qb[(bh * NSEQ + n) * DH + d] = f2bf(val * SCALE2_F);
                    else            kb[(bh * NSEQ + n) * DH + d] = f2bf(val);
                }
            }
        }
    } else {
        for (int mt = 0; mt < 4; ++mt) {
            for (int r = 0; r < 4; ++r) {
                int dv = m0 + mw + mt * 16 + quad * 4 + r;     // < 768
                float bv = bias[1536 + dv];
                int h = dv / 96, d = dv % 96;
                for (int nt = 0; nt < 4; ++nt) {
                    int ng = c0 + nw + nt * 16 + n15;
                    int b = ng >> 12, n = ng & 4095;
                    vt[((size_t)(b * HEADS + h) * DH + d) * NSEQ + n] = f2bf(acc[mt][nt][r] + bv);
                }
            }
        }
    }
}

// ---------------- Flash attention (R11/R13 structure, byte-identical) ---------------
// WG = 256 threads (4 waves x 32 q). KV tiles of 64, 64 iters, ONE barrier/iter.
// K double-buffered (2x64x128el swz), V triple-buffered (3x96x64el swz).
// body(kv): stage tile kv+1 -> barrier -> [S^T(kv+1) MFMA || exp2/pack(kv) VALU]
//           -> PV(kv) MFMA. Zero-C MFMA init (no per-iter accumulator re-zero).
__global__ __launch_bounds__(256, 2) void flash(const unsigned short* __restrict__ qb,
                                                const unsigned short* __restrict__ kb,
                                                const unsigned short* __restrict__ vt,
                                                float* __restrict__ out) {
    __shared__ unsigned short sm[34816];   // K: [0,16384) ; V: [16384, 34816) (3 slots)
    __shared__ float l_all[128];

    const int tid = threadIdx.x;
    const int lane = tid & 63, wv = tid >> 6;
    const int l31 = lane & 31, h = lane >> 5;
    const int x7 = l31 & 7;
    const int id = blockIdx.x;             // 512 blocks
    const int bh = id & 15;                // fastest -> each XCD holds 2 heads in L2
    const int q0 = (id >> 4) * 128 + wv * 32;

    const unsigned short* kgb = kb + (size_t)bh * NSEQ * DH;
    const unsigned short* vgb = vt + (size_t)bh * DH * NSEQ;

    // ---- Q B-frags in registers ----
    bf16x8 qf[6];
    {
        const unsigned short* qrow = qb + (size_t)(bh * NSEQ + q0 + l31) * DH;
#pragma unroll
        for (int ks = 0; ks < 6; ++ks)
            qf[ks] = *(const bf16x8*)&qrow[ks * 16 + h * 8];
    }

    // ---- loop-invariant LDS read offsets (swizzled) ----
    int kofs[2][6];
#pragma unroll
    for (int kt = 0; kt < 2; ++kt)
#pragma unroll
        for (int ks = 0; ks < 6; ++ks) {
            int b = 2 * ks + h;
            int bs = (b < 8) ? (b ^ x7) : (8 + ((b - 8) ^ x7));
            kofs[kt][ks] = (kt * 32 + l31) * 128 + bs * 8;
        }
    int vofs[3][4];
#pragma unroll
    for (int dt = 0; dt < 3; ++dt)
#pragma unroll
        for (int s = 0; s < 4; ++s)
            vofs[dt][s] = (dt * 32 + l31) * 64 + ((2 * s + h) ^ x7) * 8;

    // ---- staging maps: 3 K + 3 V 16B blocks per thread ----
    int goffk[3], goffv[3], wofk[3], wofv[3];
#pragma unroll
    for (int i = 0; i < 3; ++i) {
        int tb = i * 256 + tid;
        int r = tb / 12, bb = tb % 12;
        goffk[i] = r * 96 + bb * 8;
        int bs = (bb < 8) ? (bb ^ (r & 7)) : (8 + ((bb - 8) ^ (r & 7)));
        wofk[i] = r * 128 + bs * 8;
        int d = tb >> 3, b2 = tb & 7;
        goffv[i] = d * 4096 + b2 * 8;
        wofv[i] = d * 64 + ((b2 ^ (d & 7))) * 8;
    }

    const floatx16 z16 = (floatx16)(0.f);

    // ---- prologue: tile0 -> K0/V0; tile1 -> regs; S^T[0] ----
    us8 kr[3], vr[3];
    const unsigned short* kpf = kgb;
    const unsigned short* vpf = vgb;
#pragma unroll
    for (int i = 0; i < 3; ++i) { kr[i] = *(const us8*)&kpf[goffk[i]]; vr[i] = *(const us8*)&vpf[goffv[i]]; }
    kpf += 6144; vpf += 64;
#pragma unroll
    for (int i = 0; i < 3; ++i) { *(us8*)&sm[wofk[i]] = kr[i]; *(us8*)&sm[16384 + wofv[i]] = vr[i]; }
#pragma unroll
    for (int i = 0; i < 3; ++i) { kr[i] = *(const us8*)&kpf[goffk[i]]; vr[i] = *(const us8*)&vpf[goffv[i]]; }
    kpf += 6144; vpf += 64;
    __syncthreads();

    floatx16 stA[2], stB[2];
#pragma unroll
    for (int ks = 0; ks < 6; ++ks)
#pragma unroll
        for (int kt = 0; kt < 2; ++kt) {
            bf16x8 ak = *(const bf16x8*)&sm[kofs[kt][ks]];
            stA[kt] = __builtin_amdgcn_mfma_f32_32x32x16_bf16(ak, qf[ks], ks == 0 ? z16 : stA[kt], 0, 0, 0);
        }

    floatx16 o[3] = {};        // O[d-tile]: col=d=l31, rows=q
    float lsum = 0.f;

    // body(kv): cur = S^T[kv] (ready); nxt <- S^T[kv+1]. ONE barrier.
    auto body = [&](int kv, floatx16 (&cur)[2], floatx16 (&nxt)[2]) {
        if (kv < 63) {
            unsigned short* Kd = sm + ((kv + 1) & 1) * 8192;
            unsigned short* Vd = sm + 16384 + ((kv + 1) % 3) * 6144;
#pragma unroll
            for (int i = 0; i < 3; ++i) { *(us8*)&Kd[wofk[i]] = kr[i]; *(us8*)&Vd[wofv[i]] = vr[i]; }
            if (kv < 62) {
#pragma unroll
                for (int i = 0; i < 3; ++i) { kr[i] = *(const us8*)&kpf[goffk[i]]; vr[i] = *(const us8*)&vpf[goffv[i]]; }
                kpf += 6144; vpf += 64;
            }
        }
        __syncthreads();                       // tile kv+1 K/V visible

        // ---- S^T[kv+1] (matrix pipe), zero-C init ----
        if (kv < 63) {
            const unsigned short* Kn = sm + ((kv + 1) & 1) * 8192;
#pragma unroll
            for (int ks = 0; ks < 6; ++ks)
#pragma unroll
                for (int kt = 0; kt < 2; ++kt) {
                    bf16x8 ak = *(const bf16x8*)&Kn[kofs[kt][ks]];
                    nxt[kt] = __builtin_amdgcn_mfma_f32_32x32x16_bf16(ak, qf[ks], ks == 0 ? z16 : nxt[kt], 0, 0, 0);
                }
        }

        // ---- exp2/lsum/pack of tile kv (VALU pipe, overlaps S^T MFMAs) ----
#pragma unroll
        for (int kt = 0; kt < 2; ++kt)
#pragma unroll
            for (int rg = 0; rg < 16; ++rg) {
                float p = __builtin_amdgcn_exp2f(cur[kt][rg]);
                cur[kt][rg] = p;
                lsum += p;
            }
        bf16x8 pf[4];
        pf[0] = mk_pfrag(cur[0][0], cur[0][1], cur[0][2], cur[0][3],
                         cur[0][4], cur[0][5], cur[0][6], cur[0][7], h);
        pf[1] = mk_pfrag(cur[0][8], cur[0][9], cur[0][10], cur[0][11],
                         cur[0][12], cur[0][13], cur[0][14], cur[0][15], h);
        pf[2] = mk_pfrag(cur[1][0], cur[1][1], cur[1][2], cur[1][3],
                         cur[1][4], cur[1][5], cur[1][6], cur[1][7], h);
        pf[3] = mk_pfrag(cur[1][8], cur[1][9], cur[1][10], cur[1][11],
                         cur[1][12], cur[1][13], cur[1][14], cur[1][15], h);

        // ---- O += P V (tile kv) from V slot kv%3 ----
        const unsigned short* Vc = sm + 16384 + (kv % 3) * 6144;
#pragma unroll
        for (int s = 0; s < 4; ++s)
#pragma unroll
            for (int dt = 0; dt < 3; ++dt) {
                bf16x8 bv = *(const bf16x8*)&Vc[vofs[dt][s]];
                o[dt] = __builtin_amdgcn_mfma_f32_32x32x16_bf16(pf[s], bv, o[dt], 0, 0, 0);
            }
    };

    for (int kv = 0; kv < 64; kv += 2) {
        body(kv, stA, stB);
        body(kv + 1, stB, stA);
    }

    // ---- finalize lsum ----
    lsum += __shfl_xor(lsum, 32);
    if (h == 0) l_all[wv * 32 + l31] = lsum;
    __syncthreads();

    // ---- epilogue: out[b][q][hd*96 + d], fp32 ----
    const int b = bh >> 3, hd = bh & 7;
#pragma unroll
    for (int rg = 0; rg < 16; ++rg) {
        int row = (rg & 3) + 8 * (rg >> 2) + 4 * h;
        float inv = 1.0f / l_all[wv * 32 + row];
        int q = q0 + row;
        float* op = out + (size_t)(b * NSEQ + q) * DIM + hd * DH;
#pragma unroll
        for (int dt = 0; dt < 3; ++dt)
            op[dt * 32 + l31] = o[dt][rg] * inv;
    }
}

extern "C" void kernel_launch(void* const* d_in, const int* in_sizes, int n_in,
                              void* d_out, int out_size, void* d_ws, size_t ws_size,
                              hipStream_t stream) {
    const float* x    = (const float*)d_in[0];   // 2*4096*768
    const float* W    = (const float*)d_in[1];   // 768*2304
    const float* bias = (const float*)d_in[2];   // 2304
    float* out = (float*)d_out;

    char* ws = (char*)d_ws;
    unsigned short* xb = (unsigned short*)(ws);                    // 8192*768 bf16
    unsigned short* wt = (unsigned short*)(ws + 12582912);         // 2304*768 bf16 (transposed)
    unsigned short* qb = (unsigned short*)(ws + 16121856);         // [16][4096][96]
    unsigned short* kb = (unsigned short*)(ws + 28704768);         // [16][4096][96]
    unsigned short* vt = (unsigned short*)(ws + 41287680);         // [16][96][4096]

    cvt<<<7008, 256, 0, stream>>>(x, W, xb, wt);
    gemm_qkv<<<1152, 256, 0, stream>>>(xb, wt, bias, qb, kb, vt);
    flash<<<512, 256, 0, stream>>>(qb, kb, vt, out);
}